// Round 1
// baseline (15770.419 us; speedup 1.0000x reference)
//
#include <hip/hip_runtime.h>
#include <hip/hip_bf16.h>

#define BB 256
#define TT 512
#define HH 512

// ---------------- mask encoding detection ----------------
// s_onehot is a bool [B,T,2] array of 0/1 values. Depending on how the harness
// marshals bools, element storage may be u8, i32, f32, or i64. For 0/1 data:
//   u8 : bytes at idx%4==1 are real elements -> some nonzero
//   f32: 1.0f = 00 00 80 3f -> idx%4==1 bytes all zero, idx%4∈{2,3} nonzero
//   i32: 1 = 01 00 00 00 -> only idx%4==0 nonzero; idx%8==4 (odd elements) nonzero
//   i64: only idx%8==0 nonzero
__global__ void detect_k(const unsigned char* __restrict__ s, int* __restrict__ flags)
{
    int a = 0, b = 0, c = 0;
    for (int i = threadIdx.x; i < BB * TT * 2; i += blockDim.x) {
        unsigned char v = s[i];
        if (v) {
            int m = i & 3;
            if (m == 1) a = 1;
            else if (m >= 2) b = 1;
            if ((i & 7) == 4) c = 1;
        }
    }
    if (a) atomicOr(flags, 1);
    if (b) atomicOr(flags, 2);
    if (c) atomicOr(flags, 4);
}

// canon[bt] = bit0: band g valid, bit1: band r valid.  valid == (bit0|bit1).
__global__ void canon_k(const void* __restrict__ s, const int* __restrict__ flags,
                        unsigned char* __restrict__ canon)
{
    int bt = blockIdx.x * blockDim.x + threadIdx.x;
    if (bt >= BB * TT) return;
    int f = *flags;
    int sg, sr;
    if (f & 1) {
        const unsigned char* p = (const unsigned char*)s;
        sg = p[2 * bt] != 0; sr = p[2 * bt + 1] != 0;
    } else if (f & 2) {
        const float* p = (const float*)s;
        sg = p[2 * bt] != 0.0f; sr = p[2 * bt + 1] != 0.0f;
    } else if (f & 4) {
        const int* p = (const int*)s;
        sg = p[2 * bt] != 0; sr = p[2 * bt + 1] != 0;
    } else {
        const long long* p = (const long long*)s;
        sg = p[2 * bt] != 0; sr = p[2 * bt + 1] != 0;
    }
    canon[bt] = (unsigned char)(sg | (sr << 1));
}

// ---------------- W1 transpose (for coalesced FF reads) ----------------
__global__ void w1t_k(const float* __restrict__ W1, float* __restrict__ W1T)
{
    int idx = blockIdx.x * blockDim.x + threadIdx.x;
    if (idx >= HH * HH) return;
    int j = idx / HH;   // output neuron o
    int k = idx % HH;   // input h index
    W1T[k * HH + j] = W1[idx];
}

// ---------------- GRU step ----------------
// grid: (32 col-tiles, 16 batch-tiles), 256 threads.
// Col tile ct owns h-columns [ct*16, ct*16+16); the corresponding W_hh rows are
// the gate triples {j, 512+j, 1024+j}, so each thread computes hr,hz,hn for one
// (batch, h-col) pair and finishes the pointwise update locally.
template <bool DF32>
__global__ __launch_bounds__(256) void step_k(
    int t,
    const float* __restrict__ hprev, float* __restrict__ hnext,
    const unsigned char* __restrict__ canon, const float* __restrict__ dtime,
    const float* __restrict__ Wih, const float* __restrict__ Whh,
    const float* __restrict__ bih, const float* __restrict__ bhh,
    void* __restrict__ decz)
{
    __shared__ float hl[16 * 516];  // 16 batches x 512 h, padded stride 516 (16B-aligned, bank-spread)

    const int hc0 = blockIdx.x * 16;
    const int bt0 = blockIdx.y * 16;

    // stage h tile (float4)
    for (int q = threadIdx.x; q < 16 * 128; q += 256) {
        int bb = q >> 7, k4 = q & 127;
        *(float4*)(hl + bb * 516 + k4 * 4) =
            *(const float4*)(hprev + (size_t)(bt0 + bb) * HH + k4 * 4);
    }
    __syncthreads();

    const int b_l = threadIdx.x & 15;
    const int i   = threadIdx.x >> 4;
    const float* hrow = hl + b_l * 516;

    const int r0 = hc0 + i, r1 = 512 + hc0 + i, r2 = 1024 + hc0 + i;
    const float4* h4  = (const float4*)hrow;
    const float4* w04 = (const float4*)(Whh + (size_t)r0 * HH);
    const float4* w14 = (const float4*)(Whh + (size_t)r1 * HH);
    const float4* w24 = (const float4*)(Whh + (size_t)r2 * HH);

    float a0 = 0.f, a1 = 0.f, a2 = 0.f;
#pragma unroll 4
    for (int k4 = 0; k4 < 128; k4++) {
        float4 h = h4[k4];
        float4 x0 = w04[k4], x1 = w14[k4], x2 = w24[k4];
        a0 += h.x * x0.x + h.y * x0.y + h.z * x0.z + h.w * x0.w;
        a1 += h.x * x1.x + h.y * x1.y + h.z * x1.z + h.w * x1.w;
        a2 += h.x * x2.x + h.y * x2.y + h.z * x2.z + h.w * x2.w;
    }
    a0 += bhh[r0]; a1 += bhh[r1]; a2 += bhh[r2];

    const int b = bt0 + b_l;
    const unsigned char c = canon[b * TT + t];
    const float dt = dtime[b * TT + t];
    const float sg = (c & 1) ? 1.f : 0.f;
    const float sr = (c & 2) ? 1.f : 0.f;

    float xr = Wih[(size_t)r0 * 3] * dt + Wih[(size_t)r0 * 3 + 1] * sg + Wih[(size_t)r0 * 3 + 2] * sr + bih[r0];
    float xz = Wih[(size_t)r1 * 3] * dt + Wih[(size_t)r1 * 3 + 1] * sg + Wih[(size_t)r1 * 3 + 2] * sr + bih[r1];
    float xn = Wih[(size_t)r2 * 3] * dt + Wih[(size_t)r2 * 3 + 1] * sg + Wih[(size_t)r2 * 3 + 2] * sr + bih[r2];

    float r = 1.f / (1.f + expf(-(xr + a0)));
    float z = 1.f / (1.f + expf(-(xz + a1)));
    float n = tanhf(xn + r * a2);
    float hp = hrow[hc0 + i];
    float hnew = (1.f - z) * n + z * hp;
    float ho = c ? hnew : hp;

    hnext[(size_t)b * HH + hc0 + i] = ho;
    size_t di = ((size_t)b * TT + t) * HH + hc0 + i;
    if (DF32) ((float*)decz)[di] = ho;
    else      ((__hip_bfloat16*)decz)[di] = __float2bfloat16(ho);
}

// ---------------- FF head: decx = W2 . relu(W1 . decz + b1) + b2 ----------------
// 512 threads, 16 rows per block. Thread j owns hidden neuron j for all 16 rows.
template <bool DF32>
__global__ __launch_bounds__(512) void ff_k(
    const void* __restrict__ decz, const float* __restrict__ W1T,
    const float* __restrict__ b1, const float* __restrict__ W2,
    const float* __restrict__ b2, float* __restrict__ decx)
{
    __shared__ float xl[16 * 512];
    __shared__ float red[8];

    const int row0 = blockIdx.x * 16;
    for (int idx = threadIdx.x; idx < 16 * 512; idx += 512) {
        int rr = idx >> 9, k = idx & 511;
        size_t gi = (size_t)(row0 + rr) * HH + k;
        float v = DF32 ? ((const float*)decz)[gi]
                       : __bfloat162float(((const __hip_bfloat16*)decz)[gi]);
        xl[rr * 512 + k] = v;
    }
    __syncthreads();

    const int j = threadIdx.x;
    float acc[16];
#pragma unroll
    for (int rr = 0; rr < 16; rr++) acc[rr] = 0.f;

    for (int k = 0; k < 512; k++) {
        float wv = W1T[k * 512 + j];
#pragma unroll
        for (int rr = 0; rr < 16; rr++) acc[rr] += xl[rr * 512 + k] * wv;
    }

    const float w2j = W2[j];
    const float b1j = b1[j];
    for (int rr = 0; rr < 16; rr++) {
        float v = w2j * fmaxf(acc[rr] + b1j, 0.f);
#pragma unroll
        for (int o = 32; o > 0; o >>= 1) v += __shfl_down(v, o, 64);
        if ((threadIdx.x & 63) == 0) red[threadIdx.x >> 6] = v;
        __syncthreads();
        if (threadIdx.x == 0) {
            float s = 0.f;
#pragma unroll
            for (int w = 0; w < 8; w++) s += red[w];
            decx[row0 + rr] = s + b2[0];
        }
        __syncthreads();
    }
}

// ---------------- serial -> parallel scatter ----------------
__global__ void scatter_k(const unsigned char* __restrict__ canon,
                          const float* __restrict__ decx, float* __restrict__ out)
{
    int id = blockIdx.x * blockDim.x + threadIdx.x;
    if (id >= 2 * BB) return;
    int kb = id >> 8, b = id & 255;
    int cnt = 0;
    for (int t = 0; t < TT; t++) {
        unsigned char c = canon[b * TT + t];
        if ((c >> kb) & 1) {
            out[((size_t)kb * BB + b) * TT + cnt] = decx[b * TT + t];
            cnt++;
        }
    }
}

extern "C" void kernel_launch(void* const* d_in, const int* in_sizes, int n_in,
                              void* d_out, int out_size, void* d_ws, size_t ws_size,
                              hipStream_t stream)
{
    const float* dtime    = (const float*)d_in[0];
    const void*  s_onehot = d_in[1];
    // d_in[2] (onehot/valid) is never read: valid == s_g | s_r by construction.
    const float* encz = (const float*)d_in[3];
    const float* Wih  = (const float*)d_in[4];
    const float* Whh  = (const float*)d_in[5];
    const float* bih  = (const float*)d_in[6];
    const float* bhh  = (const float*)d_in[7];
    const float* W1   = (const float*)d_in[8];
    const float* b1   = (const float*)d_in[9];
    const float* W2   = (const float*)d_in[10];
    const float* b2   = (const float*)d_in[11];

    char* ws = (char*)d_ws;
    int* flags = (int*)ws;
    unsigned char* canon = (unsigned char*)(ws + 256);
    float* hbuf = (float*)(ws + 256 + BB * TT);
    float* decx = hbuf + 2 * BB * HH;
    float* W1T  = decx + BB * TT;
    char*  decz = (char*)(W1T + HH * HH);
    size_t base = (size_t)(decz - ws);
    bool df32 = ws_size >= base + (size_t)BB * TT * HH * sizeof(float);

    hipMemsetAsync(flags, 0, 256, stream);
    detect_k<<<1, 256, 0, stream>>>((const unsigned char*)s_onehot, flags);
    canon_k<<<(BB * TT + 255) / 256, 256, 0, stream>>>(s_onehot, flags, canon);
    hipMemcpyAsync(hbuf, encz, (size_t)BB * HH * sizeof(float),
                   hipMemcpyDeviceToDevice, stream);
    w1t_k<<<(HH * HH + 255) / 256, 256, 0, stream>>>(W1, W1T);

    for (int t = 0; t < TT; t++) {
        const float* hp = hbuf + (size_t)(t & 1) * BB * HH;
        float* hn = hbuf + (size_t)((t + 1) & 1) * BB * HH;
        if (df32)
            step_k<true><<<dim3(32, 16), 256, 0, stream>>>(t, hp, hn, canon, dtime,
                                                           Wih, Whh, bih, bhh, decz);
        else
            step_k<false><<<dim3(32, 16), 256, 0, stream>>>(t, hp, hn, canon, dtime,
                                                            Wih, Whh, bih, bhh, decz);
    }

    if (df32)
        ff_k<true><<<BB * TT / 16, 512, 0, stream>>>(decz, W1T, b1, W2, b2, decx);
    else
        ff_k<false><<<BB * TT / 16, 512, 0, stream>>>(decz, W1T, b1, W2, b2, decx);

    hipMemsetAsync(d_out, 0, (size_t)out_size * sizeof(float), stream);
    scatter_k<<<2, 256, 0, stream>>>(canon, decx, (float*)d_out);
}